// Round 14
// baseline (434.598 us; speedup 1.0000x reference)
//
#include <hip/hip_runtime.h>
#include <math.h>

#define H 300
#define NLEAF 4096

typedef unsigned int  uint;
typedef unsigned short ushort;
typedef __attribute__((ext_vector_type(8))) short  short8;
typedef __attribute__((ext_vector_type(4))) float  f32x4;

__device__ __forceinline__ float sigmoidf_(float x) { return 1.0f / (1.0f + expf(-x)); }

__device__ __forceinline__ ushort f2bf(float f)
{
    uint u = __float_as_uint(f);
    u += 0x7FFF + ((u >> 16) & 1);
    return (ushort)(u >> 16);
}
__device__ __forceinline__ uint2 pack4(float4 v)
{
    uint2 w;
    w.x = (uint)f2bf(v.x) | ((uint)f2bf(v.y) << 16);
    w.y = (uint)f2bf(v.z) | ((uint)f2bf(v.w) << 16);
    return w;
}

// ---- per-wave MFMA GEMM: NT 16-wide col-tiles, KSTEPS k-steps of 32 ----
// A in LDS (row stride AS ushorts, 16 rows). B global col-major (col stride KS).
// Fragment layout (guide §3): A row=lane%16, k=(lane>>4)*8+i; B col=lane%16;
// C/D col=lane&15, row=(lane>>4)*4+reg (m89-verified).
template<int NT, int KSTEPS, int AS, int KS>
__device__ __forceinline__ void mfma_gemm(const ushort* A_lds, const ushort* __restrict__ B,
                                          int colT0, int lane, f32x4* acc)
{
    const ushort* Ap = A_lds + (lane & 15) * AS + ((lane >> 4) * 8);
    const ushort* Bp[NT];
    #pragma unroll
    for (int t = 0; t < NT; ++t)
        Bp[t] = B + (long)(colT0 + 16 * t + (lane & 15)) * KS + ((lane >> 4) * 8);

    short8 aA, aB, bA[NT], bB[NT];
    aA = *(const short8*)Ap;
    #pragma unroll
    for (int t = 0; t < NT; ++t) bA[t] = *(const short8*)Bp[t];

    int s = 0;
    #pragma unroll 1
    for (; s + 2 < KSTEPS; s += 2) {
        aB = *(const short8*)(Ap + (s + 1) * 32);
        #pragma unroll
        for (int t = 0; t < NT; ++t) bB[t] = *(const short8*)(Bp[t] + (s + 1) * 32);
        #pragma unroll
        for (int t = 0; t < NT; ++t)
            acc[t] = __builtin_amdgcn_mfma_f32_16x16x32_bf16(aA, bA[t], acc[t], 0, 0, 0);
        aA = *(const short8*)(Ap + (s + 2) * 32);
        #pragma unroll
        for (int t = 0; t < NT; ++t) bA[t] = *(const short8*)(Bp[t] + (s + 2) * 32);
        #pragma unroll
        for (int t = 0; t < NT; ++t)
            acc[t] = __builtin_amdgcn_mfma_f32_16x16x32_bf16(aB, bB[t], acc[t], 0, 0, 0);
    }
    if (KSTEPS - s == 2) {
        aB = *(const short8*)(Ap + (s + 1) * 32);
        #pragma unroll
        for (int t = 0; t < NT; ++t) bB[t] = *(const short8*)(Bp[t] + (s + 1) * 32);
        #pragma unroll
        for (int t = 0; t < NT; ++t)
            acc[t] = __builtin_amdgcn_mfma_f32_16x16x32_bf16(aA, bA[t], acc[t], 0, 0, 0);
        #pragma unroll
        for (int t = 0; t < NT; ++t)
            acc[t] = __builtin_amdgcn_mfma_f32_16x16x32_bf16(aB, bB[t], acc[t], 0, 0, 0);
    } else {
        #pragma unroll
        for (int t = 0; t < NT; ++t)
            acc[t] = __builtin_amdgcn_mfma_f32_16x16x32_bf16(aA, bA[t], acc[t], 0, 0, 0);
    }
}

// ---- one-time weight transpose+convert to bf16, K padded per-half to 304 ----
// WArz [640 cols][608]: cols 0-299 r (Wr rows 350-649 | 0x4 | 650-949 | 0x4),
//   300-319 zero, 320-619 z (Wz same), 620-639 zero.
// WuTp [320][608]: Wu rows 300-599 | 0 | 600-899 | 0.
// WLzu [640][320]: cols 0-299 Wz rows 0-299 (+20 zero rows), 320-619 Wu.
__global__ __launch_bounds__(256) void convert_k(
    const float* __restrict__ Wr, const float* __restrict__ Wz,
    const float* __restrict__ Wu,
    ushort* __restrict__ WArz, ushort* __restrict__ WuTp, ushort* __restrict__ WLzu)
{
    int c = blockIdx.x;          // 0..639
    int tid = threadIdx.x;
    int gate = (c >= 320);
    int cc = gate ? c - 320 : c;
    const float* WA = gate ? Wz : Wr;
    for (int r = tid; r < 608; r += 256) {
        float v = 0.f;
        if (cc < 300) {
            if (r < 300) v = WA[(350 + r) * H + cc];
            else if (r >= 304 && r < 604) v = WA[(r + 346) * H + cc];
        }
        WArz[(long)c * 608 + r] = f2bf(v);
    }
    const float* WL = gate ? Wu : Wz;
    for (int r = tid; r < 320; r += 256) {
        float v = (cc < 300 && r < 300) ? WL[r * H + cc] : 0.f;
        WLzu[(long)c * 320 + r] = f2bf(v);
    }
    if (c < 320) {
        for (int r = tid; r < 608; r += 256) {
            float v = 0.f;
            if (c < 300) {
                if (r < 300) v = Wu[(300 + r) * H + c];
                else if (r >= 304 && r < 604) v = Wu[(r + 296) * H + c];
            }
            WuTp[(long)c * 608 + r] = f2bf(v);
        }
    }
}

// tag_r[t][k] = br[k] + sum_j tag_table[t][j]*Wr[300+j][k]  (likewise tag_z)
__global__ __launch_bounds__(320) void tag_kernel(
    const float* __restrict__ tag_table,
    const float* __restrict__ Wr, const float* __restrict__ br,
    const float* __restrict__ Wz, const float* __restrict__ bz,
    float* __restrict__ tag_r, float* __restrict__ tag_z)
{
    int t = blockIdx.x;
    int k = threadIdx.x;
    __shared__ float te[50];
    if (k < 50) te[k] = tag_table[t * 50 + k];
    __syncthreads();
    if (k < H) {
        float ar = br[k], az = bz[k];
        #pragma unroll 10
        for (int j = 0; j < 50; ++j) {
            float tv = te[j];
            ar = fmaf(tv, Wr[(H + j) * H + k], ar);
            az = fmaf(tv, Wz[(H + j) * H + k], az);
        }
        tag_r[t * H + k] = ar;
        tag_z[t * H + k] = az;
    }
}

// ---- Leaf (MFMA): 16 nodes/block; z kept in registers (same cols as u tiles).
__global__ __launch_bounds__(256, 1) void leaf_mfma_k(
    const int* __restrict__ word_ids, const int* __restrict__ tag_ids,
    const float* __restrict__ word_table, const ushort* __restrict__ WLzu,
    const float* __restrict__ bu, const float* __restrict__ tag_z,
    float* __restrict__ out)
{
    __shared__ ushort Abf[16 * 328];     // 16 rows x (320 + 8 pad)
    int tid = threadIdx.x;
    int node0 = blockIdx.x * 16;

    for (int idx = tid; idx < 16 * 82; idx += 256) {
        int j = idx / 82, q = idx - j * 82;
        char* rowb = (char*)(Abf + j * 328);
        if (q < 75) {
            float4 v = ((const float4*)(word_table + (long)word_ids[node0 + j] * H))[q];
            *(uint2*)(rowb + q * 8) = pack4(v);
        } else {
            *(uint2*)(rowb + q * 8) = make_uint2(0u, 0u);   // bytes 600..655
        }
    }
    __syncthreads();

    int wv = tid >> 6, lane = tid & 63;
    int jrow = (lane >> 4) * 4;
    int tg[4];
    #pragma unroll
    for (int q = 0; q < 4; ++q) tg[q] = tag_ids[node0 + jrow + q];

    f32x4 accZ[5];
    #pragma unroll
    for (int t = 0; t < 5; ++t) accZ[t] = (f32x4)(0.f);
    mfma_gemm<5, 10, 328, 320>(Abf, WLzu, wv * 80, lane, accZ);

    float zz[5][4];
    #pragma unroll
    for (int t = 0; t < 5; ++t) {
        int c = wv * 80 + t * 16 + (lane & 15);
        #pragma unroll
        for (int q = 0; q < 4; ++q)
            if (c < 300) zz[t][q] = sigmoidf_(accZ[t][q] + tag_z[tg[q] * H + c]);
    }

    f32x4 accU[5];
    #pragma unroll
    for (int t = 0; t < 5; ++t) accU[t] = (f32x4)(0.f);
    mfma_gemm<5, 10, 328, 320>(Abf, WLzu, 320 + wv * 80, lane, accU);
    #pragma unroll
    for (int t = 0; t < 5; ++t) {
        int c = wv * 80 + t * 16 + (lane & 15);
        #pragma unroll
        for (int q = 0; q < 4; ++q) {
            if (c < 300) {
                int jn = jrow + q;
                float u = tanhf(accU[t][q] + bu[c]);
                out[(long)(node0 + jn) * H + c] = (1.f - zz[t][q]) * u;
            }
        }
    }
}

// ---- Fused internal level: one block = 16 nodes x full job.
// stage X bf16 -> gates r,z GEMMs -> (z,S in regs; rx bf16 IN-PLACE into Abf)
// -> u GEMM -> h. Handles partial blocks (node masking + OOB-guarded reads).
__global__ __launch_bounds__(256, 1) void level_fused_k(
    const int* __restrict__ tag_ids, const ushort* __restrict__ WArz,
    const ushort* __restrict__ WuTp, const float* __restrict__ bu,
    const float* __restrict__ tag_r, const float* __restrict__ tag_z,
    float* __restrict__ out, int off, int prevOff, int m, float* __restrict__ dup)
{
    __shared__ ushort Abf[16 * 616];     // 16 x (608 + 8 pad)
    int tid = threadIdx.x;
    int node0 = blockIdx.x * 16;

    for (int idx = tid; idx < 16 * 154; idx += 256) {
        int j = idx / 154, q = idx - j * 154;
        char* rowb = (char*)(Abf + j * 616);
        bool valid = (node0 + j) < m;
        if (q < 75) {
            uint2 w = make_uint2(0u, 0u);
            if (valid) {
                float4 v = ((const float4*)(out + (long)(prevOff + 2 * (node0 + j)) * H))[q];
                w = pack4(v);
            }
            *(uint2*)(rowb + q * 8) = w;
        } else if (q < 150) {
            int qq = q - 75;
            uint2 w = make_uint2(0u, 0u);
            if (valid) {
                float4 v = ((const float4*)(out + (long)(prevOff + 2 * (node0 + j) + 1) * H))[qq];
                w = pack4(v);
            }
            *(uint2*)(rowb + 608 + qq * 8) = w;
        } else {
            int pb = (q == 150) ? 600 : (1208 + (q - 151) * 8);   // pads 300-303, 604-615
            *(uint2*)(rowb + pb) = make_uint2(0u, 0u);
        }
    }
    __syncthreads();

    int wv = tid >> 6, lane = tid & 63;
    int jrow = (lane >> 4) * 4;

    f32x4 accR[5], accZ[5];
    #pragma unroll
    for (int t = 0; t < 5; ++t) { accR[t] = (f32x4)(0.f); accZ[t] = (f32x4)(0.f); }
    mfma_gemm<5, 19, 616, 608>(Abf, WArz, wv * 80, lane, accR);
    mfma_gemm<5, 19, 616, 608>(Abf, WArz, 320 + wv * 80, lane, accZ);
    __syncthreads();   // all GEMM reads of Abf complete before in-place rx write

    int tg[4];
    #pragma unroll
    for (int q = 0; q < 4; ++q) {
        int gn = node0 + jrow + q;
        tg[q] = tag_ids[off + (gn < m ? gn : 0)];
    }

    float zr[5][4], Sr[5][4];
    #pragma unroll
    for (int t = 0; t < 5; ++t) {
        int c = wv * 80 + t * 16 + (lane & 15);
        #pragma unroll
        for (int q = 0; q < 4; ++q) {
            int jn = jrow + q, gn = node0 + jn;
            if (c < 300 && gn < m) {
                float lh = out[(long)(prevOff + 2 * gn) * H + c];
                float rh = out[(long)(prevOff + 2 * gn + 1) * H + c];
                float r  = sigmoidf_(accR[t][q] + tag_r[tg[q] * H + c]);
                Sr[t][q] = lh + rh;
                zr[t][q] = sigmoidf_(accZ[t][q] + tag_z[tg[q] * H + c]);
                Abf[jn * 616 + c]       = f2bf(r * lh);
                Abf[jn * 616 + 304 + c] = f2bf(r * rh);
            }
        }
    }
    __syncthreads();   // rx visible to all waves

    f32x4 accU[5];
    #pragma unroll
    for (int t = 0; t < 5; ++t) accU[t] = (f32x4)(0.f);
    mfma_gemm<5, 19, 616, 608>(Abf, WuTp, wv * 80, lane, accU);
    #pragma unroll
    for (int t = 0; t < 5; ++t) {
        int c = wv * 80 + t * 16 + (lane & 15);
        #pragma unroll
        for (int q = 0; q < 4; ++q) {
            int jn = jrow + q, gn = node0 + jn;
            if (c < 300 && gn < m) {
                float u = tanhf(accU[t][q] + bu[c]);
                float z = zr[t][q];
                float h = z * Sr[t][q] + (1.f - z) * u;
                out[(long)(off + gn) * H + c] = h;
                if (dup && gn == 0) dup[c] = h;
            }
        }
    }
}

extern "C" void kernel_launch(void* const* d_in, const int* in_sizes, int n_in,
                              void* d_out, int out_size, void* d_ws, size_t ws_size,
                              hipStream_t stream)
{
    const int*   word_ids   = (const int*)  d_in[0];
    const int*   tag_ids    = (const int*)  d_in[1];
    const float* word_table = (const float*)d_in[2];
    const float* tag_table  = (const float*)d_in[3];
    const float* Wr         = (const float*)d_in[4];
    const float* br         = (const float*)d_in[5];
    const float* Wz         = (const float*)d_in[6];
    const float* bz         = (const float*)d_in[7];
    const float* Wu         = (const float*)d_in[8];
    const float* bu         = (const float*)d_in[9];
    float* out = (float*)d_out;

    float* tag_r = (float*)d_ws;                 // 18000 f32
    float* tag_z = tag_r + 18000;                // 18000 f32
    ushort* WArz = (ushort*)(tag_z + 18000);     // 640*608 bf16
    ushort* WuTp = WArz + 640L * 608;            // 320*608
    ushort* WLzu = WuTp + 320L * 608;            // 640*320

    convert_k<<<640, 256, 0, stream>>>(Wr, Wz, Wu, WArz, WuTp, WLzu);
    tag_kernel<<<60, 320, 0, stream>>>(tag_table, Wr, br, Wz, bz, tag_r, tag_z);

    leaf_mfma_k<<<NLEAF / 16, 256, 0, stream>>>(
        word_ids, tag_ids, word_table, WLzu, bu, tag_z, out);

    float* finalDup = out + (long)8191 * H;
    int off = NLEAF, prevOff = 0;
    for (int m = 2048; m >= 1; m >>= 1) {
        int grid = (m + 15) / 16;
        level_fused_k<<<grid, 256, 0, stream>>>(
            tag_ids, WArz, WuTp, bu, tag_r, tag_z, out, off, prevOff, m,
            (m == 1) ? finalDup : nullptr);
        prevOff = off;
        off += m;
    }
}

// Round 15
// 388.449 us; speedup vs baseline: 1.1188x; 1.1188x over previous
//
#include <hip/hip_runtime.h>
#include <math.h>

#define H 300
#define NLEAF 4096

typedef unsigned int  uint;
typedef unsigned short ushort;
typedef __attribute__((ext_vector_type(8))) short  short8;
typedef __attribute__((ext_vector_type(4))) float  f32x4;

__device__ __forceinline__ float sigmoidf_(float x) { return 1.0f / (1.0f + expf(-x)); }

__device__ __forceinline__ ushort f2bf(float f)
{
    uint u = __float_as_uint(f);
    u += 0x7FFF + ((u >> 16) & 1);
    return (ushort)(u >> 16);
}
__device__ __forceinline__ uint2 pack4(float4 v)
{
    uint2 w;
    w.x = (uint)f2bf(v.x) | ((uint)f2bf(v.y) << 16);
    w.y = (uint)f2bf(v.z) | ((uint)f2bf(v.w) << 16);
    return w;
}

// ---- per-wave MFMA GEMM: NT 16-wide col-tiles, KSTEPS k-steps of 32 ----
// A in LDS (row stride AS ushorts, 16 rows). B global col-major (col stride KS).
// Fragment layout (guide §3): A row=lane%16, k=(lane>>4)*8+i; B col=lane%16;
// C/D col=lane&15, row=(lane>>4)*4+reg (m89-verified).
// K offsets: pass A_lds+koff and B+koff (within-row/col shift).
template<int NT, int KSTEPS, int AS, int KS>
__device__ __forceinline__ void mfma_gemm(const ushort* A_lds, const ushort* __restrict__ B,
                                          int colT0, int lane, f32x4* acc)
{
    const ushort* Ap = A_lds + (lane & 15) * AS + ((lane >> 4) * 8);
    const ushort* Bp[NT];
    #pragma unroll
    for (int t = 0; t < NT; ++t)
        Bp[t] = B + (long)(colT0 + 16 * t + (lane & 15)) * KS + ((lane >> 4) * 8);

    short8 aA, aB, bA[NT], bB[NT];
    aA = *(const short8*)Ap;
    #pragma unroll
    for (int t = 0; t < NT; ++t) bA[t] = *(const short8*)Bp[t];

    int s = 0;
    #pragma unroll 1
    for (; s + 2 < KSTEPS; s += 2) {
        aB = *(const short8*)(Ap + (s + 1) * 32);
        #pragma unroll
        for (int t = 0; t < NT; ++t) bB[t] = *(const short8*)(Bp[t] + (s + 1) * 32);
        #pragma unroll
        for (int t = 0; t < NT; ++t)
            acc[t] = __builtin_amdgcn_mfma_f32_16x16x32_bf16(aA, bA[t], acc[t], 0, 0, 0);
        aA = *(const short8*)(Ap + (s + 2) * 32);
        #pragma unroll
        for (int t = 0; t < NT; ++t) bA[t] = *(const short8*)(Bp[t] + (s + 2) * 32);
        #pragma unroll
        for (int t = 0; t < NT; ++t)
            acc[t] = __builtin_amdgcn_mfma_f32_16x16x32_bf16(aB, bB[t], acc[t], 0, 0, 0);
    }
    if (KSTEPS - s == 2) {
        aB = *(const short8*)(Ap + (s + 1) * 32);
        #pragma unroll
        for (int t = 0; t < NT; ++t) bB[t] = *(const short8*)(Bp[t] + (s + 1) * 32);
        #pragma unroll
        for (int t = 0; t < NT; ++t)
            acc[t] = __builtin_amdgcn_mfma_f32_16x16x32_bf16(aA, bA[t], acc[t], 0, 0, 0);
        #pragma unroll
        for (int t = 0; t < NT; ++t)
            acc[t] = __builtin_amdgcn_mfma_f32_16x16x32_bf16(aB, bB[t], acc[t], 0, 0, 0);
    } else {
        #pragma unroll
        for (int t = 0; t < NT; ++t)
            acc[t] = __builtin_amdgcn_mfma_f32_16x16x32_bf16(aA, bA[t], acc[t], 0, 0, 0);
    }
}

// ---- one-time weight transpose+convert to bf16, K padded per-half to 304 ----
__global__ __launch_bounds__(256) void convert_k(
    const float* __restrict__ Wr, const float* __restrict__ Wz,
    const float* __restrict__ Wu,
    ushort* __restrict__ WArz, ushort* __restrict__ WuTp, ushort* __restrict__ WLzu)
{
    int c = blockIdx.x;          // 0..639
    int tid = threadIdx.x;
    int gate = (c >= 320);
    int cc = gate ? c - 320 : c;
    const float* WA = gate ? Wz : Wr;
    for (int r = tid; r < 608; r += 256) {
        float v = 0.f;
        if (cc < 300) {
            if (r < 300) v = WA[(350 + r) * H + cc];
            else if (r >= 304 && r < 604) v = WA[(r + 346) * H + cc];
        }
        WArz[(long)c * 608 + r] = f2bf(v);
    }
    const float* WL = gate ? Wu : Wz;
    for (int r = tid; r < 320; r += 256) {
        float v = (cc < 300 && r < 300) ? WL[r * H + cc] : 0.f;
        WLzu[(long)c * 320 + r] = f2bf(v);
    }
    if (c < 320) {
        for (int r = tid; r < 608; r += 256) {
            float v = 0.f;
            if (c < 300) {
                if (r < 300) v = Wu[(300 + r) * H + c];
                else if (r >= 304 && r < 604) v = Wu[(r + 296) * H + c];
            }
            WuTp[(long)c * 608 + r] = f2bf(v);
        }
    }
}

// tag_r[t][k] = br[k] + sum_j tag_table[t][j]*Wr[300+j][k]  (likewise tag_z)
__global__ __launch_bounds__(320) void tag_kernel(
    const float* __restrict__ tag_table,
    const float* __restrict__ Wr, const float* __restrict__ br,
    const float* __restrict__ Wz, const float* __restrict__ bz,
    float* __restrict__ tag_r, float* __restrict__ tag_z)
{
    int t = blockIdx.x;
    int k = threadIdx.x;
    __shared__ float te[50];
    if (k < 50) te[k] = tag_table[t * 50 + k];
    __syncthreads();
    if (k < H) {
        float ar = br[k], az = bz[k];
        #pragma unroll 10
        for (int j = 0; j < 50; ++j) {
            float tv = te[j];
            ar = fmaf(tv, Wr[(H + j) * H + k], ar);
            az = fmaf(tv, Wz[(H + j) * H + k], az);
        }
        tag_r[t * H + k] = ar;
        tag_z[t * H + k] = az;
    }
}

// ---- Leaf (MFMA, 512 thr / 8 waves): waves 0-3 z-cols, waves 4-7 u-cols.
__global__ __launch_bounds__(512, 1) void leaf_mfma_k(
    const int* __restrict__ word_ids, const int* __restrict__ tag_ids,
    const float* __restrict__ word_table, const ushort* __restrict__ WLzu,
    const float* __restrict__ bu, const float* __restrict__ tag_z,
    float* __restrict__ out)
{
    __shared__ ushort Abf[16 * 328];     // 16 rows x (320 + 8 pad)
    __shared__ float zbuf[16][304];
    int tid = threadIdx.x;
    int node0 = blockIdx.x * 16;

    for (int idx = tid; idx < 16 * 82; idx += 512) {
        int j = idx / 82, q = idx - j * 82;
        char* rowb = (char*)(Abf + j * 328);
        if (q < 75) {
            float4 v = ((const float4*)(word_table + (long)word_ids[node0 + j] * H))[q];
            *(uint2*)(rowb + q * 8) = pack4(v);
        } else {
            *(uint2*)(rowb + q * 8) = make_uint2(0u, 0u);   // bytes 600..655
        }
    }
    __syncthreads();

    int wv = tid >> 6, lane = tid & 63;
    int jrow = (lane >> 4) * 4;

    f32x4 acc[5];
    #pragma unroll
    for (int t = 0; t < 5; ++t) acc[t] = (f32x4)(0.f);

    if (wv < 4) {                       // z GEMM
        mfma_gemm<5, 10, 328, 320>(Abf, WLzu, wv * 80, lane, acc);
        int tg[4];
        #pragma unroll
        for (int q = 0; q < 4; ++q) tg[q] = tag_ids[node0 + jrow + q];
        #pragma unroll
        for (int t = 0; t < 5; ++t) {
            int c = wv * 80 + t * 16 + (lane & 15);
            #pragma unroll
            for (int q = 0; q < 4; ++q)
                if (c < 300) zbuf[jrow + q][c] = sigmoidf_(acc[t][q] + tag_z[tg[q] * H + c]);
        }
    } else {                            // u GEMM
        mfma_gemm<5, 10, 328, 320>(Abf, WLzu, 320 + (wv - 4) * 80, lane, acc);
    }
    __syncthreads();
    if (wv >= 4) {
        #pragma unroll
        for (int t = 0; t < 5; ++t) {
            int c = (wv - 4) * 80 + t * 16 + (lane & 15);
            #pragma unroll
            for (int q = 0; q < 4; ++q) {
                if (c < 300) {
                    int jn = jrow + q;
                    float u = tanhf(acc[t][q] + bu[c]);
                    out[(long)(node0 + jn) * H + c] = (1.f - zbuf[jn][c]) * u;
                }
            }
        }
    }
}

// ---- Fused internal level body (512 thr / 8 waves, 16 nodes):
// gates: 8 waves x 80 cols of 640-col r|z GEMM. r-waves keep S in regs,
// write rx bf16 in-place to Abf; z-waves -> zbuf. u: K-split (w0-3 ksteps
// 0-9, w4-7 ksteps 10-18 -> pbuf partials), reduce + epilogue on w0-3.
__device__ __forceinline__ void fused_body(
    const int* __restrict__ tag_ids, const ushort* __restrict__ WArz,
    const ushort* __restrict__ WuTp, const float* __restrict__ bu,
    const float* __restrict__ tag_r, const float* __restrict__ tag_z,
    float* __restrict__ out, int off, int prevOff, int m, float* __restrict__ dup,
    int node0, int tid, ushort* Abf, float (*zbuf)[304], float (*pbuf)[64][21])
{
    for (int idx = tid; idx < 16 * 154; idx += 512) {
        int j = idx / 154, q = idx - j * 154;
        char* rowb = (char*)(Abf + j * 616);
        bool valid = (node0 + j) < m;
        if (q < 75) {
            uint2 w = make_uint2(0u, 0u);
            if (valid) {
                float4 v = ((const float4*)(out + (long)(prevOff + 2 * (node0 + j)) * H))[q];
                w = pack4(v);
            }
            *(uint2*)(rowb + q * 8) = w;
        } else if (q < 150) {
            int qq = q - 75;
            uint2 w = make_uint2(0u, 0u);
            if (valid) {
                float4 v = ((const float4*)(out + (long)(prevOff + 2 * (node0 + j) + 1) * H))[qq];
                w = pack4(v);
            }
            *(uint2*)(rowb + 608 + qq * 8) = w;
        } else {
            int pb = (q == 150) ? 600 : (1208 + (q - 151) * 8);   // pads 300-303, 604-615
            *(uint2*)(rowb + pb) = make_uint2(0u, 0u);
        }
    }
    __syncthreads();

    int wv = tid >> 6, lane = tid & 63;
    int jrow = (lane >> 4) * 4;
    int tg[4];
    #pragma unroll
    for (int q = 0; q < 4; ++q) {
        int gn = node0 + jrow + q;
        tg[q] = tag_ids[off + (gn < m ? gn : 0)];
    }

    // gates GEMM: wave wv covers cols wv*80 .. wv*80+79 of [r|z] space
    f32x4 accG[5];
    #pragma unroll
    for (int t = 0; t < 5; ++t) accG[t] = (f32x4)(0.f);
    mfma_gemm<5, 19, 616, 608>(Abf, WArz, wv * 80, lane, accG);
    __syncthreads();   // all gates reads of Abf done before in-place rx write

    float Sr[5][4];
    if (wv < 4) {
        #pragma unroll
        for (int t = 0; t < 5; ++t) {
            int c = wv * 80 + t * 16 + (lane & 15);
            #pragma unroll
            for (int q = 0; q < 4; ++q) {
                int jn = jrow + q, gn = node0 + jn;
                if (c < 300 && gn < m) {
                    float lh = out[(long)(prevOff + 2 * gn) * H + c];
                    float rh = out[(long)(prevOff + 2 * gn + 1) * H + c];
                    float r  = sigmoidf_(accG[t][q] + tag_r[tg[q] * H + c]);
                    Sr[t][q] = lh + rh;
                    Abf[jn * 616 + c]       = f2bf(r * lh);
                    Abf[jn * 616 + 304 + c] = f2bf(r * rh);
                }
            }
        }
    } else {
        #pragma unroll
        for (int t = 0; t < 5; ++t) {
            int cz = (wv - 4) * 80 + t * 16 + (lane & 15);
            #pragma unroll
            for (int q = 0; q < 4; ++q) {
                int jn = jrow + q, gn = node0 + jn;
                if (cz < 300 && gn < m)
                    zbuf[jn][cz] = sigmoidf_(accG[t][q] + tag_z[tg[q] * H + cz]);
            }
        }
    }
    __syncthreads();   // rx + zbuf visible

    // u GEMM, K-split across wave halves
    f32x4 accU[5];
    #pragma unroll
    for (int t = 0; t < 5; ++t) accU[t] = (f32x4)(0.f);
    if (wv < 4) {
        mfma_gemm<5, 10, 616, 608>(Abf, WuTp, wv * 80, lane, accU);
    } else {
        mfma_gemm<5, 9, 616, 608>(Abf + 320, WuTp + 320, (wv - 4) * 80, lane, accU);
        #pragma unroll
        for (int t = 0; t < 5; ++t)
            #pragma unroll
            for (int q = 0; q < 4; ++q)
                pbuf[wv - 4][lane][t * 4 + q] = accU[t][q];
    }
    __syncthreads();
    if (wv < 4) {
        #pragma unroll
        for (int t = 0; t < 5; ++t) {
            int c = wv * 80 + t * 16 + (lane & 15);
            #pragma unroll
            for (int q = 0; q < 4; ++q) {
                int jn = jrow + q, gn = node0 + jn;
                if (c < 300 && gn < m) {
                    float a = accU[t][q] + pbuf[wv][lane][t * 4 + q];
                    float u = tanhf(a + bu[c]);
                    float z = zbuf[jn][c];
                    float h = z * Sr[t][q] + (1.f - z) * u;
                    out[(long)(off + gn) * H + c] = h;
                    if (dup && gn == 0) dup[c] = h;
                }
            }
        }
    }
}

__global__ __launch_bounds__(512, 1) void level_fused_k(
    const int* __restrict__ tag_ids, const ushort* __restrict__ WArz,
    const ushort* __restrict__ WuTp, const float* __restrict__ bu,
    const float* __restrict__ tag_r, const float* __restrict__ tag_z,
    float* __restrict__ out, int off, int prevOff, int m)
{
    __shared__ ushort Abf[16 * 616];
    __shared__ float zbuf[16][304];
    __shared__ float pbuf[4][64][21];
    fused_body(tag_ids, WArz, WuTp, bu, tag_r, tag_z, out, off, prevOff, m,
               nullptr, blockIdx.x * 16, threadIdx.x, Abf, zbuf, pbuf);
}

// Tail: levels m=16,8,4,2,1 in ONE block (intra-block global visibility via
// __syncthreads, R8-proven). dup = final_state row at m==1.
__global__ __launch_bounds__(512, 1) void tail_fused_k(
    const int* __restrict__ tag_ids, const ushort* __restrict__ WArz,
    const ushort* __restrict__ WuTp, const float* __restrict__ bu,
    const float* __restrict__ tag_r, const float* __restrict__ tag_z,
    float* __restrict__ out, float* __restrict__ finalDup)
{
    __shared__ ushort Abf[16 * 616];
    __shared__ float zbuf[16][304];
    __shared__ float pbuf[4][64][21];
    int off = 8160, prevOff = 8128;
    for (int m = 16; m >= 1; m >>= 1) {
        fused_body(tag_ids, WArz, WuTp, bu, tag_r, tag_z, out, off, prevOff, m,
                   (m == 1) ? finalDup : nullptr, 0, threadIdx.x, Abf, zbuf, pbuf);
        __syncthreads();
        prevOff = off;
        off += m;
    }
}

extern "C" void kernel_launch(void* const* d_in, const int* in_sizes, int n_in,
                              void* d_out, int out_size, void* d_ws, size_t ws_size,
                              hipStream_t stream)
{
    const int*   word_ids   = (const int*)  d_in[0];
    const int*   tag_ids    = (const int*)  d_in[1];
    const float* word_table = (const float*)d_in[2];
    const float* tag_table  = (const float*)d_in[3];
    const float* Wr         = (const float*)d_in[4];
    const float* br         = (const float*)d_in[5];
    const float* Wz         = (const float*)d_in[6];
    const float* bz         = (const float*)d_in[7];
    const float* Wu         = (const float*)d_in[8];
    const float* bu         = (const float*)d_in[9];
    float* out = (float*)d_out;

    float* tag_r = (float*)d_ws;                 // 18000 f32
    float* tag_z = tag_r + 18000;                // 18000 f32
    ushort* WArz = (ushort*)(tag_z + 18000);     // 640*608 bf16
    ushort* WuTp = WArz + 640L * 608;            // 320*608
    ushort* WLzu = WuTp + 320L * 608;            // 640*320

    convert_k<<<640, 256, 0, stream>>>(Wr, Wz, Wu, WArz, WuTp, WLzu);
    tag_kernel<<<60, 320, 0, stream>>>(tag_table, Wr, br, Wz, bz, tag_r, tag_z);

    leaf_mfma_k<<<NLEAF / 16, 512, 0, stream>>>(
        word_ids, tag_ids, word_table, WLzu, bu, tag_z, out);

    int off = NLEAF, prevOff = 0;
    for (int m = 2048; m >= 32; m >>= 1) {
        level_fused_k<<<m / 16, 512, 0, stream>>>(
            tag_ids, WArz, WuTp, bu, tag_r, tag_z, out, off, prevOff, m);
        prevOff = off;
        off += m;
    }

    float* finalDup = out + (long)8191 * H;
    tail_fused_k<<<1, 512, 0, stream>>>(
        tag_ids, WArz, WuTp, bu, tag_r, tag_z, out, finalDup);
}

// Round 16
// 366.668 us; speedup vs baseline: 1.1853x; 1.0594x over previous
//
#include <hip/hip_runtime.h>
#include <math.h>

#define H 300
#define NLEAF 4096

typedef unsigned int  uint;
typedef unsigned short ushort;
typedef __attribute__((ext_vector_type(8))) short  short8;
typedef __attribute__((ext_vector_type(4))) float  f32x4;

__device__ __forceinline__ float sigmoidf_(float x) { return 1.0f / (1.0f + expf(-x)); }

__device__ __forceinline__ ushort f2bf(float f)
{
    uint u = __float_as_uint(f);
    u += 0x7FFF + ((u >> 16) & 1);
    return (ushort)(u >> 16);
}
__device__ __forceinline__ uint2 pack4(float4 v)
{
    uint2 w;
    w.x = (uint)f2bf(v.x) | ((uint)f2bf(v.y) << 16);
    w.y = (uint)f2bf(v.z) | ((uint)f2bf(v.w) << 16);
    return w;
}

// ---- per-wave MFMA GEMM: NT 16-wide col-tiles, KSTEPS k-steps of 32 ----
// A in LDS (row stride AS ushorts, 16 rows). B global col-major (col stride KS).
// A row=lane%16, k=(lane>>4)*8+i; B col=lane%16; C/D col=lane&15,
// row=(lane>>4)*4+reg (m89-verified). For K-offset: shift BOTH base pointers
// by kstart*32 (within-row / within-col contiguous).
template<int NT, int KSTEPS, int AS, int KS>
__device__ __forceinline__ void mfma_gemm(const ushort* A_lds, const ushort* __restrict__ B,
                                          int colT0, int lane, f32x4* acc)
{
    const ushort* Ap = A_lds + (lane & 15) * AS + ((lane >> 4) * 8);
    const ushort* Bp[NT];
    #pragma unroll
    for (int t = 0; t < NT; ++t)
        Bp[t] = B + (long)(colT0 + 16 * t + (lane & 15)) * KS + ((lane >> 4) * 8);

    short8 aA, aB, bA[NT], bB[NT];
    aA = *(const short8*)Ap;
    #pragma unroll
    for (int t = 0; t < NT; ++t) bA[t] = *(const short8*)Bp[t];

    int s = 0;
    #pragma unroll 1
    for (; s + 2 < KSTEPS; s += 2) {
        aB = *(const short8*)(Ap + (s + 1) * 32);
        #pragma unroll
        for (int t = 0; t < NT; ++t) bB[t] = *(const short8*)(Bp[t] + (s + 1) * 32);
        #pragma unroll
        for (int t = 0; t < NT; ++t)
            acc[t] = __builtin_amdgcn_mfma_f32_16x16x32_bf16(aA, bA[t], acc[t], 0, 0, 0);
        aA = *(const short8*)(Ap + (s + 2) * 32);
        #pragma unroll
        for (int t = 0; t < NT; ++t) bA[t] = *(const short8*)(Bp[t] + (s + 2) * 32);
        #pragma unroll
        for (int t = 0; t < NT; ++t)
            acc[t] = __builtin_amdgcn_mfma_f32_16x16x32_bf16(aB, bB[t], acc[t], 0, 0, 0);
    }
    if (KSTEPS - s == 2) {
        aB = *(const short8*)(Ap + (s + 1) * 32);
        #pragma unroll
        for (int t = 0; t < NT; ++t) bB[t] = *(const short8*)(Bp[t] + (s + 1) * 32);
        #pragma unroll
        for (int t = 0; t < NT; ++t)
            acc[t] = __builtin_amdgcn_mfma_f32_16x16x32_bf16(aA, bA[t], acc[t], 0, 0, 0);
        #pragma unroll
        for (int t = 0; t < NT; ++t)
            acc[t] = __builtin_amdgcn_mfma_f32_16x16x32_bf16(aB, bB[t], acc[t], 0, 0, 0);
    } else {
        #pragma unroll
        for (int t = 0; t < NT; ++t)
            acc[t] = __builtin_amdgcn_mfma_f32_16x16x32_bf16(aA, bA[t], acc[t], 0, 0, 0);
    }
}

// ---- one-time weight transpose+convert to bf16, K padded per-half to 304 ----
__global__ __launch_bounds__(256) void convert_k(
    const float* __restrict__ Wr, const float* __restrict__ Wz,
    const float* __restrict__ Wu,
    ushort* __restrict__ WArz, ushort* __restrict__ WuTp, ushort* __restrict__ WLzu)
{
    int c = blockIdx.x;          // 0..639
    int tid = threadIdx.x;
    int gate = (c >= 320);
    int cc = gate ? c - 320 : c;
    const float* WA = gate ? Wz : Wr;
    for (int r = tid; r < 608; r += 256) {
        float v = 0.f;
        if (cc < 300) {
            if (r < 300) v = WA[(350 + r) * H + cc];
            else if (r >= 304 && r < 604) v = WA[(r + 346) * H + cc];
        }
        WArz[(long)c * 608 + r] = f2bf(v);
    }
    const float* WL = gate ? Wu : Wz;
    for (int r = tid; r < 320; r += 256) {
        float v = (cc < 300 && r < 300) ? WL[r * H + cc] : 0.f;
        WLzu[(long)c * 320 + r] = f2bf(v);
    }
    if (c < 320) {
        for (int r = tid; r < 608; r += 256) {
            float v = 0.f;
            if (c < 300) {
                if (r < 300) v = Wu[(300 + r) * H + c];
                else if (r >= 304 && r < 604) v = Wu[(r + 296) * H + c];
            }
            WuTp[(long)c * 608 + r] = f2bf(v);
        }
    }
}

// tag_r[t][k] = br[k] + sum_j tag_table[t][j]*Wr[300+j][k]  (likewise tag_z)
__global__ __launch_bounds__(320) void tag_kernel(
    const float* __restrict__ tag_table,
    const float* __restrict__ Wr, const float* __restrict__ br,
    const float* __restrict__ Wz, const float* __restrict__ bz,
    float* __restrict__ tag_r, float* __restrict__ tag_z)
{
    int t = blockIdx.x;
    int k = threadIdx.x;
    __shared__ float te[50];
    if (k < 50) te[k] = tag_table[t * 50 + k];
    __syncthreads();
    if (k < H) {
        float ar = br[k], az = bz[k];
        #pragma unroll 10
        for (int j = 0; j < 50; ++j) {
            float tv = te[j];
            ar = fmaf(tv, Wr[(H + j) * H + k], ar);
            az = fmaf(tv, Wz[(H + j) * H + k], az);
        }
        tag_r[t * H + k] = ar;
        tag_z[t * H + k] = az;
    }
}

// ---- Leaf (MFMA, 512 thr / 8 waves): waves 0-3 z-cols, waves 4-7 u-cols.
__global__ __launch_bounds__(512, 1) void leaf_mfma_k(
    const int* __restrict__ word_ids, const int* __restrict__ tag_ids,
    const float* __restrict__ word_table, const ushort* __restrict__ WLzu,
    const float* __restrict__ bu, const float* __restrict__ tag_z,
    float* __restrict__ out)
{
    __shared__ ushort Abf[16 * 328];
    __shared__ float zbuf[16][304];
    int tid = threadIdx.x;
    int node0 = blockIdx.x * 16;

    for (int idx = tid; idx < 16 * 82; idx += 512) {
        int j = idx / 82, q = idx - j * 82;
        char* rowb = (char*)(Abf + j * 328);
        if (q < 75) {
            float4 v = ((const float4*)(word_table + (long)word_ids[node0 + j] * H))[q];
            *(uint2*)(rowb + q * 8) = pack4(v);
        } else {
            *(uint2*)(rowb + q * 8) = make_uint2(0u, 0u);
        }
    }
    __syncthreads();

    int wv = tid >> 6, lane = tid & 63;
    int jrow = (lane >> 4) * 4;

    f32x4 acc[5];
    #pragma unroll
    for (int t = 0; t < 5; ++t) acc[t] = (f32x4)(0.f);

    if (wv < 4) {
        mfma_gemm<5, 10, 328, 320>(Abf, WLzu, wv * 80, lane, acc);
        int tg[4];
        #pragma unroll
        for (int q = 0; q < 4; ++q) tg[q] = tag_ids[node0 + jrow + q];
        #pragma unroll
        for (int t = 0; t < 5; ++t) {
            int c = wv * 80 + t * 16 + (lane & 15);
            #pragma unroll
            for (int q = 0; q < 4; ++q)
                if (c < 300) zbuf[jrow + q][c] = sigmoidf_(acc[t][q] + tag_z[tg[q] * H + c]);
        }
    } else {
        mfma_gemm<5, 10, 328, 320>(Abf, WLzu, 320 + (wv - 4) * 80, lane, acc);
    }
    __syncthreads();
    if (wv >= 4) {
        #pragma unroll
        for (int t = 0; t < 5; ++t) {
            int c = (wv - 4) * 80 + t * 16 + (lane & 15);
            #pragma unroll
            for (int q = 0; q < 4; ++q) {
                if (c < 300) {
                    int jn = jrow + q;
                    float u = tanhf(acc[t][q] + bu[c]);
                    out[(long)(node0 + jn) * H + c] = (1.f - zbuf[jn][c]) * u;
                }
            }
        }
    }
}

// ---- Fused internal level (512 thr / 8 waves, 16 nodes), for m >= 256 ----
__device__ __forceinline__ void fused_body(
    const int* __restrict__ tag_ids, const ushort* __restrict__ WArz,
    const ushort* __restrict__ WuTp, const float* __restrict__ bu,
    const float* __restrict__ tag_r, const float* __restrict__ tag_z,
    float* __restrict__ out, int off, int prevOff, int m,
    int node0, int tid, ushort* Abf, float (*zbuf)[304], float (*pbuf)[64][21])
{
    for (int idx = tid; idx < 16 * 154; idx += 512) {
        int j = idx / 154, q = idx - j * 154;
        char* rowb = (char*)(Abf + j * 616);
        bool valid = (node0 + j) < m;
        if (q < 75) {
            uint2 w = make_uint2(0u, 0u);
            if (valid) {
                float4 v = ((const float4*)(out + (long)(prevOff + 2 * (node0 + j)) * H))[q];
                w = pack4(v);
            }
            *(uint2*)(rowb + q * 8) = w;
        } else if (q < 150) {
            int qq = q - 75;
            uint2 w = make_uint2(0u, 0u);
            if (valid) {
                float4 v = ((const float4*)(out + (long)(prevOff + 2 * (node0 + j) + 1) * H))[qq];
                w = pack4(v);
            }
            *(uint2*)(rowb + 608 + qq * 8) = w;
        } else {
            int pb = (q == 150) ? 600 : (1208 + (q - 151) * 8);
            *(uint2*)(rowb + pb) = make_uint2(0u, 0u);
        }
    }
    __syncthreads();

    int wv = tid >> 6, lane = tid & 63;
    int jrow = (lane >> 4) * 4;
    int tg[4];
    #pragma unroll
    for (int q = 0; q < 4; ++q) {
        int gn = node0 + jrow + q;
        tg[q] = tag_ids[off + (gn < m ? gn : 0)];
    }

    f32x4 accG[5];
    #pragma unroll
    for (int t = 0; t < 5; ++t) accG[t] = (f32x4)(0.f);
    mfma_gemm<5, 19, 616, 608>(Abf, WArz, wv * 80, lane, accG);
    __syncthreads();

    float Sr[5][4];
    if (wv < 4) {
        #pragma unroll
        for (int t = 0; t < 5; ++t) {
            int c = wv * 80 + t * 16 + (lane & 15);
            #pragma unroll
            for (int q = 0; q < 4; ++q) {
                int jn = jrow + q, gn = node0 + jn;
                if (c < 300 && gn < m) {
                    float lh = out[(long)(prevOff + 2 * gn) * H + c];
                    float rh = out[(long)(prevOff + 2 * gn + 1) * H + c];
                    float r  = sigmoidf_(accG[t][q] + tag_r[tg[q] * H + c]);
                    Sr[t][q] = lh + rh;
                    Abf[jn * 616 + c]       = f2bf(r * lh);
                    Abf[jn * 616 + 304 + c] = f2bf(r * rh);
                }
            }
        }
    } else {
        #pragma unroll
        for (int t = 0; t < 5; ++t) {
            int cz = (wv - 4) * 80 + t * 16 + (lane & 15);
            #pragma unroll
            for (int q = 0; q < 4; ++q) {
                int jn = jrow + q, gn = node0 + jn;
                if (cz < 300 && gn < m)
                    zbuf[jn][cz] = sigmoidf_(accG[t][q] + tag_z[tg[q] * H + cz]);
            }
        }
    }
    __syncthreads();

    f32x4 accU[5];
    #pragma unroll
    for (int t = 0; t < 5; ++t) accU[t] = (f32x4)(0.f);
    if (wv < 4) {
        mfma_gemm<5, 10, 616, 608>(Abf, WuTp, wv * 80, lane, accU);
    } else {
        mfma_gemm<5, 9, 616, 608>(Abf + 320, WuTp + 320, (wv - 4) * 80, lane, accU);
        #pragma unroll
        for (int t = 0; t < 5; ++t)
            #pragma unroll
            for (int q = 0; q < 4; ++q)
                pbuf[wv - 4][lane][t * 4 + q] = accU[t][q];
    }
    __syncthreads();
    if (wv < 4) {
        #pragma unroll
        for (int t = 0; t < 5; ++t) {
            int c = wv * 80 + t * 16 + (lane & 15);
            #pragma unroll
            for (int q = 0; q < 4; ++q) {
                int jn = jrow + q, gn = node0 + jn;
                if (c < 300 && gn < m) {
                    float a = accU[t][q] + pbuf[wv][lane][t * 4 + q];
                    float u = tanhf(a + bu[c]);
                    float z = zbuf[jn][c];
                    out[(long)(off + gn) * H + c] = z * Sr[t][q] + (1.f - z) * u;
                }
            }
        }
    }
}

__global__ __launch_bounds__(512, 1) void level_fused_k(
    const int* __restrict__ tag_ids, const ushort* __restrict__ WArz,
    const ushort* __restrict__ WuTp, const float* __restrict__ bu,
    const float* __restrict__ tag_r, const float* __restrict__ tag_z,
    float* __restrict__ out, int off, int prevOff, int m)
{
    __shared__ ushort Abf[16 * 616];
    __shared__ float zbuf[16][304];
    __shared__ float pbuf[4][64][21];
    fused_body(tag_ids, WArz, WuTp, bu, tag_r, tag_z, out, off, prevOff, m,
               blockIdx.x * 16, threadIdx.x, Abf, zbuf, pbuf);
}

// ---- Small levels (m <= 128): per-level 2-kernel column+K-split ----
// gates: block = (Mtile, colblock of 80 cols in 640 r|z space), 256 thr,
// 4 waves K-split 19 ksteps (5,5,5,4), LDS-reduce, wave-0 epilogue.
__global__ __launch_bounds__(256, 1) void split_gates_k(
    const int* __restrict__ tag_ids, const ushort* __restrict__ WArz,
    const float* __restrict__ tag_r, const float* __restrict__ tag_z,
    const float* __restrict__ out,
    float* __restrict__ zws, float* __restrict__ Sws, ushort* __restrict__ rxws,
    int off, int prevOff, int m)
{
    __shared__ ushort Abf[16 * 616];
    __shared__ float pbuf[3][64][20];
    int tid = threadIdx.x;
    int mt = blockIdx.x >> 3, cb = blockIdx.x & 7;
    int node0 = mt * 16;

    for (int idx = tid; idx < 16 * 154; idx += 256) {
        int j = idx / 154, q = idx - j * 154;
        char* rowb = (char*)(Abf + j * 616);
        bool valid = (node0 + j) < m;
        if (q < 75) {
            uint2 w = make_uint2(0u, 0u);
            if (valid) {
                float4 v = ((const float4*)(out + (long)(prevOff + 2 * (node0 + j)) * H))[q];
                w = pack4(v);
            }
            *(uint2*)(rowb + q * 8) = w;
        } else if (q < 150) {
            int qq = q - 75;
            uint2 w = make_uint2(0u, 0u);
            if (valid) {
                float4 v = ((const float4*)(out + (long)(prevOff + 2 * (node0 + j) + 1) * H))[qq];
                w = pack4(v);
            }
            *(uint2*)(rowb + 608 + qq * 8) = w;
        } else {
            int pb = (q == 150) ? 600 : (1208 + (q - 151) * 8);
            *(uint2*)(rowb + pb) = make_uint2(0u, 0u);
        }
    }
    __syncthreads();

    int wv = tid >> 6, lane = tid & 63;
    int colT0 = cb * 80;
    f32x4 acc[5];
    #pragma unroll
    for (int t = 0; t < 5; ++t) acc[t] = (f32x4)(0.f);
    if (wv < 3) {
        // compiler needs constant kstart offsets: dispatch
        if (wv == 0)      mfma_gemm<5, 5, 616, 608>(Abf,        WArz,        colT0, lane, acc);
        else if (wv == 1) mfma_gemm<5, 5, 616, 608>(Abf + 160,  WArz + 160,  colT0, lane, acc);
        else              mfma_gemm<5, 5, 616, 608>(Abf + 320,  WArz + 320,  colT0, lane, acc);
    } else {
        mfma_gemm<5, 4, 616, 608>(Abf + 480, WArz + 480, colT0, lane, acc);
    }
    if (wv > 0) {
        #pragma unroll
        for (int t = 0; t < 5; ++t)
            #pragma unroll
            for (int q = 0; q < 4; ++q)
                pbuf[wv - 1][lane][t * 4 + q] = acc[t][q];
    }
    __syncthreads();
    if (wv == 0) {
        int jrow = (lane >> 4) * 4;
        #pragma unroll
        for (int t = 0; t < 5; ++t) {
            int c = colT0 + t * 16 + (lane & 15);
            #pragma unroll
            for (int q = 0; q < 4; ++q) {
                int jn = jrow + q, gn = node0 + jn;
                float a = acc[t][q] + pbuf[0][lane][t * 4 + q]
                        + pbuf[1][lane][t * 4 + q] + pbuf[2][lane][t * 4 + q];
                if (c < 320) {                      // r gate
                    if (c < 300 && gn < m) {
                        int tg = tag_ids[off + gn];
                        float r  = sigmoidf_(a + tag_r[tg * H + c]);
                        float lh = out[(long)(prevOff + 2 * gn) * H + c];
                        float rh = out[(long)(prevOff + 2 * gn + 1) * H + c];
                        Sws[gn * 304 + c] = lh + rh;
                        rxws[(long)gn * 608 + c]       = f2bf(r * lh);
                        rxws[(long)gn * 608 + 304 + c] = f2bf(r * rh);
                    } else if (c >= 300 && c < 304 && gn < m) {
                        rxws[(long)gn * 608 + c]       = 0;
                        rxws[(long)gn * 608 + 304 + c] = 0;
                    }
                } else {                            // z gate
                    int cz = c - 320;
                    if (cz < 300 && gn < m) {
                        int tg = tag_ids[off + gn];
                        zws[gn * 304 + cz] = sigmoidf_(a + tag_z[tg * H + cz]);
                    }
                }
            }
        }
    }
}

// u: block = (Mtile, 80-col slice of 320), 256 thr, 4-way K-split.
__global__ __launch_bounds__(256, 1) void split_u_k(
    const ushort* __restrict__ WuTp, const float* __restrict__ bu,
    const float* __restrict__ zws, const float* __restrict__ Sws,
    const ushort* __restrict__ rxws,
    float* __restrict__ out, int off, int m, float* __restrict__ dup)
{
    __shared__ ushort Abf[16 * 616];
    __shared__ float pbuf[3][64][20];
    int tid = threadIdx.x;
    int mt = blockIdx.x >> 2, ub = blockIdx.x & 3;
    int node0 = mt * 16;

    for (int idx = tid; idx < 16 * 77; idx += 256) {
        int j = idx / 77, q = idx - j * 77;
        uint4* dst = (uint4*)(Abf + j * 616) + q;
        if (q < 76 && (node0 + j) < m)
            *dst = ((const uint4*)(rxws + (long)(node0 + j) * 608))[q];
        else
            *dst = make_uint4(0u, 0u, 0u, 0u);
    }
    __syncthreads();

    int wv = tid >> 6, lane = tid & 63;
    int colT0 = ub * 80;
    f32x4 acc[5];
    #pragma unroll
    for (int t = 0; t < 5; ++t) acc[t] = (f32x4)(0.f);
    if (wv < 3) {
        if (wv == 0)      mfma_gemm<5, 5, 616, 608>(Abf,       WuTp,       colT0, lane, acc);
        else if (wv == 1) mfma_gemm<5, 5, 616, 608>(Abf + 160, WuTp + 160, colT0, lane, acc);
        else              mfma_gemm<5, 5, 616, 608>(Abf + 320, WuTp + 320, colT0, lane, acc);
    } else {
        mfma_gemm<5, 4, 616, 608>(Abf + 480, WuTp + 480, colT0, lane, acc);
    }
    if (wv > 0) {
        #pragma unroll
        for (int t = 0; t < 5; ++t)
            #pragma unroll
            for (int q = 0; q < 4; ++q)
                pbuf[wv - 1][lane][t * 4 + q] = acc[t][q];
    }
    __syncthreads();
    if (wv == 0) {
        int jrow = (lane >> 4) * 4;
        #pragma unroll
        for (int t = 0; t < 5; ++t) {
            int c = colT0 + t * 16 + (lane & 15);
            #pragma unroll
            for (int q = 0; q < 4; ++q) {
                int jn = jrow + q, gn = node0 + jn;
                if (c < 300 && gn < m) {
                    float a = acc[t][q] + pbuf[0][lane][t * 4 + q]
                            + pbuf[1][lane][t * 4 + q] + pbuf[2][lane][t * 4 + q];
                    float u = tanhf(a + bu[c]);
                    float z = zws[gn * 304 + c];
                    float h = z * Sws[gn * 304 + c] + (1.f - z) * u;
                    out[(long)(off + gn) * H + c] = h;
                    if (dup && gn == 0) dup[c] = h;
                }
            }
        }
    }
}

extern "C" void kernel_launch(void* const* d_in, const int* in_sizes, int n_in,
                              void* d_out, int out_size, void* d_ws, size_t ws_size,
                              hipStream_t stream)
{
    const int*   word_ids   = (const int*)  d_in[0];
    const int*   tag_ids    = (const int*)  d_in[1];
    const float* word_table = (const float*)d_in[2];
    const float* tag_table  = (const float*)d_in[3];
    const float* Wr         = (const float*)d_in[4];
    const float* br         = (const float*)d_in[5];
    const float* Wz         = (const float*)d_in[6];
    const float* bz         = (const float*)d_in[7];
    const float* Wu         = (const float*)d_in[8];
    const float* bu         = (const float*)d_in[9];
    float* out = (float*)d_out;

    float* tag_r = (float*)d_ws;                 // 18000 f32
    float* tag_z = tag_r + 18000;                // 18000 f32
    float* zws   = tag_z + 18000;                // 128*304 f32
    float* Sws   = zws + 128 * 304;              // 128*304 f32
    ushort* rxws = (ushort*)(Sws + 128 * 304);   // 128*608 bf16
    ushort* WArz = rxws + 128L * 608;            // 640*608 bf16
    ushort* WuTp = WArz + 640L * 608;            // 320*608
    ushort* WLzu = WuTp + 320L * 608;            // 640*320

    convert_k<<<640, 256, 0, stream>>>(Wr, Wz, Wu, WArz, WuTp, WLzu);
    tag_kernel<<<60, 320, 0, stream>>>(tag_table, Wr, br, Wz, bz, tag_r, tag_z);

    leaf_mfma_k<<<NLEAF / 16, 512, 0, stream>>>(
        word_ids, tag_ids, word_table, WLzu, bu, tag_z, out);

    float* finalDup = out + (long)8191 * H;
    int off = NLEAF, prevOff = 0;
    for (int m = 2048; m >= 1; m >>= 1) {
        if (m >= 256) {
            level_fused_k<<<m / 16, 512, 0, stream>>>(
                tag_ids, WArz, WuTp, bu, tag_r, tag_z, out, off, prevOff, m);
        } else {
            int nMt = (m + 15) / 16;
            split_gates_k<<<nMt * 8, 256, 0, stream>>>(
                tag_ids, WArz, tag_r, tag_z, out, zws, Sws, rxws, off, prevOff, m);
            split_u_k<<<nMt * 4, 256, 0, stream>>>(
                WuTp, bu, zws, Sws, rxws, out, off, m, (m == 1) ? finalDup : nullptr);
        }
        prevOff = off;
        off += m;
    }
}